// Round 16
// baseline (227.276 us; speedup 1.0000x reference)
//
#include <hip/hip_runtime.h>

#define C_DIM 256
#define N_TOK 4096
#define DQK_  32
#define SCALE_Q 0.17677669529663687f   // 1/sqrt(32)
#define SCALE_Q2 0.25504345023688654f  // 1/sqrt(32) * log2(e): scores in log2 domain

typedef unsigned short u16;
typedef __attribute__((ext_vector_type(8))) short bf16x8;
typedef __attribute__((ext_vector_type(16))) float f32x16;

__device__ __forceinline__ u16 f2b(float f) {
  unsigned u = __builtin_bit_cast(unsigned, f);
  unsigned r = (u + 0x7fffu + ((u >> 16) & 1u)) >> 16;
  return (u16)r;
}
__device__ __forceinline__ unsigned splitw(float v) {
  unsigned h = f2b(v);
  float hf = __builtin_bit_cast(float, h << 16);
  unsigned l = f2b(v - hf);
  return h | (l << 16);
}
__device__ __forceinline__ unsigned cvtpk(float lo, float hi) {
  unsigned r;
  asm("v_cvt_pk_bf16_f32 %0, %1, %2" : "=v"(r) : "v"(lo), "v"(hi));
  return r;
}

// ---------------- prep: act transpose->bf16 planes + weight split planes ----------------
__global__ __launch_bounds__(256) void prep_kernel(
    const float* __restrict__ x, const float* __restrict__ y,
    u16* __restrict__ xhi, u16* __restrict__ yhi,
    const float* __restrict__ Wv, const float* __restrict__ W1, const float* __restrict__ W2,
    const float* __restrict__ Wq, const float* __restrict__ Wk,
    u16* __restrict__ Wvh, u16* __restrict__ Wvl,
    u16* __restrict__ W1h, u16* __restrict__ W1l,
    u16* __restrict__ W2h, u16* __restrict__ W2l,
    u16* __restrict__ Wqh, u16* __restrict__ Wql,
    u16* __restrict__ Wkh, u16* __restrict__ Wkl)
{
  __shared__ float tile[64][65];
  int bid = blockIdx.x;
  int t = threadIdx.x;
  if (bid < 2048) {
    int bx = bid & 63, by = (bid >> 6) & 3, z = bid >> 8;
    const float* src = (z < 4 ? x : y) + (size_t)(z & 3) * C_DIM * N_TOK;
    u16* dhi = (z < 4 ? xhi : yhi) + (size_t)(z & 3) * N_TOK * C_DIM;
    int m0 = bx * 64, c0 = by * 64;
    #pragma unroll
    for (int pp = 0; pp < 4; ++pp) {
      int c = pp*16 + (t >> 4), m = (t & 15)*4;
      float4 v = *(const float4*)(src + (size_t)(c0 + c)*N_TOK + m0 + m);
      tile[c][m] = v.x; tile[c][m+1] = v.y; tile[c][m+2] = v.z; tile[c][m+3] = v.w;
    }
    __syncthreads();
    int m = t >> 2, cg = (t & 3) * 16;
    unsigned hw[8];
    #pragma unroll
    for (int j2 = 0; j2 < 8; ++j2)
      hw[j2] = (unsigned)f2b(tile[cg + 2*j2][m]) | ((unsigned)f2b(tile[cg + 2*j2 + 1][m]) << 16);
    size_t base = (size_t)(m0 + m)*C_DIM + c0 + cg;
    *(uint4*)(dhi + base)     = make_uint4(hw[0], hw[1], hw[2], hw[3]);
    *(uint4*)(dhi + base + 8) = make_uint4(hw[4], hw[5], hw[6], hw[7]);
  } else {
    int wb = bid - 2048;
    int which, base;
    if (wb < 768) { which = wb >> 8; base = wb & 255; }
    else if (wb < 800) { which = 3; base = wb - 768; }
    else { which = 4; base = wb - 800; }
    const float* src = which == 0 ? Wv : which == 1 ? W1 : which == 2 ? W2 : which == 3 ? Wq : Wk;
    u16* dhi = which == 0 ? Wvh : which == 1 ? W1h : which == 2 ? W2h : which == 3 ? Wqh : Wkh;
    u16* dlo = which == 0 ? Wvl : which == 1 ? W1l : which == 2 ? W2l : which == 3 ? Wql : Wkl;
    int idx = base*256 + t;
    unsigned s = splitw(src[idx]);
    dhi[idx] = (u16)(s & 0xffffu);
    dlo[idx] = (u16)(s >> 16);
  }
}

// ---------------- bodies for the fused proj_v / proj_qk launch ----------------
__device__ __forceinline__ void gemm_v_body(
    char* lds, int bx, int by, int bb,
    const u16* __restrict__ Ahi0, const u16* __restrict__ Ahi1, size_t aStride,
    const u16* __restrict__ Bhi, const u16* __restrict__ Blo,
    const float* __restrict__ bias, u16* __restrict__ OutBase, size_t oStride)
{
  const u16* Ah = (bb < 4 ? Ahi0 : Ahi1) + (size_t)(bb & 3) * aStride;
  int l0 = bx * 128;
  int s0 = by * 128;
  u16* Ob = OutBase + (size_t)bb * oStride;

  char* ldsAh = lds;
  char* ldsBh = lds + 16384;
  char* ldsBl = lds + 32768;

  int t = threadIdx.x;
  int w = t >> 6, lane = t & 63, g = lane >> 5, l31 = lane & 31;
  int lw = (w & 1) * 64, sw = (w >> 1) * 64;
  int swz = (l31 & 7) << 4;

  f32x16 acc[2][2];
  #pragma unroll
  for (int i = 0; i < 2; ++i)
    #pragma unroll
    for (int j = 0; j < 2; ++j)
      #pragma unroll
      for (int r = 0; r < 16; ++r) acc[i][j][r] = 0.f;

  uint4 rAh[4], rBh[4], rBl[4];
  #pragma unroll
  for (int c = 0; c < 4; ++c) {
    int idx = c*256 + t, row = idx >> 3, slot = idx & 7;
    rAh[c] = *(const uint4*)(Ah  + (size_t)(l0 + row)*C_DIM + slot*8);
    rBh[c] = *(const uint4*)(Bhi + (size_t)(s0 + row)*C_DIM + slot*8);
    rBl[c] = *(const uint4*)(Blo + (size_t)(s0 + row)*C_DIM + slot*8);
  }
  for (int bk = 0; bk < 4; ++bk) {
    __syncthreads();
    #pragma unroll
    for (int c = 0; c < 4; ++c) {
      int idx = c*256 + t, row = idx >> 3, slot = idx & 7;
      int off = row*128 + ((slot*16) ^ ((row & 7) << 4));
      *(uint4*)(ldsAh + off) = rAh[c];
      *(uint4*)(ldsBh + off) = rBh[c];
      *(uint4*)(ldsBl + off) = rBl[c];
    }
    __syncthreads();
    if (bk < 3) {
      #pragma unroll
      for (int c = 0; c < 4; ++c) {
        int idx = c*256 + t, row = idx >> 3, slot = idx & 7;
        rAh[c] = *(const uint4*)(Ah  + (size_t)(l0 + row)*C_DIM + (bk+1)*64 + slot*8);
        rBh[c] = *(const uint4*)(Bhi + (size_t)(s0 + row)*C_DIM + (bk+1)*64 + slot*8);
        rBl[c] = *(const uint4*)(Blo + (size_t)(s0 + row)*C_DIM + (bk+1)*64 + slot*8);
      }
    }
    #pragma unroll
    for (int ks = 0; ks < 4; ++ks) {
      int ko = ks*32 + g*16;
      bf16x8 ah0 = *(const bf16x8*)(ldsAh + (lw + l31)*128      + (ko ^ swz));
      bf16x8 ah1 = *(const bf16x8*)(ldsAh + (lw + 32 + l31)*128 + (ko ^ swz));
      bf16x8 bh0 = *(const bf16x8*)(ldsBh + (sw + l31)*128      + (ko ^ swz));
      bf16x8 bh1 = *(const bf16x8*)(ldsBh + (sw + 32 + l31)*128 + (ko ^ swz));
      bf16x8 bl0 = *(const bf16x8*)(ldsBl + (sw + l31)*128      + (ko ^ swz));
      bf16x8 bl1 = *(const bf16x8*)(ldsBl + (sw + 32 + l31)*128 + (ko ^ swz));
      acc[0][0] = __builtin_amdgcn_mfma_f32_32x32x16_bf16(ah0, bh0, acc[0][0], 0,0,0);
      acc[0][1] = __builtin_amdgcn_mfma_f32_32x32x16_bf16(ah0, bh1, acc[0][1], 0,0,0);
      acc[1][0] = __builtin_amdgcn_mfma_f32_32x32x16_bf16(ah1, bh0, acc[1][0], 0,0,0);
      acc[1][1] = __builtin_amdgcn_mfma_f32_32x32x16_bf16(ah1, bh1, acc[1][1], 0,0,0);
      acc[0][0] = __builtin_amdgcn_mfma_f32_32x32x16_bf16(ah0, bl0, acc[0][0], 0,0,0);
      acc[0][1] = __builtin_amdgcn_mfma_f32_32x32x16_bf16(ah0, bl1, acc[0][1], 0,0,0);
      acc[1][0] = __builtin_amdgcn_mfma_f32_32x32x16_bf16(ah1, bl0, acc[1][0], 0,0,0);
      acc[1][1] = __builtin_amdgcn_mfma_f32_32x32x16_bf16(ah1, bl1, acc[1][1], 0,0,0);
    }
  }

  for (int h = 0; h < 2; ++h) {
    __syncthreads();
    if ((w >> 1) == h) {
      #pragma unroll
      for (int j = 0; j < 2; ++j) {
        int sl = j*32 + l31;
        float bv = bias[s0 + h*64 + sl];
        #pragma unroll
        for (int i = 0; i < 2; ++i)
          #pragma unroll
          for (int q = 0; q < 4; ++q) {
            int lbase = lw + i*32 + 8*q + 4*g;
            unsigned w0 = (unsigned)f2b(acc[i][j][q*4+0] + bv)
                        | ((unsigned)f2b(acc[i][j][q*4+1] + bv) << 16);
            unsigned w1 = (unsigned)f2b(acc[i][j][q*4+2] + bv)
                        | ((unsigned)f2b(acc[i][j][q*4+3] + bv) << 16);
            *(uint2*)(lds + sl*272 + lbase*2) = make_uint2(w0, w1);
          }
      }
    }
    __syncthreads();
    #pragma unroll
    for (int p = 0; p < 4; ++p) {
      int s = p*16 + (t >> 4), col = (t & 15)*8;
      uint4 v = *(const uint4*)(lds + s*272 + col*2);
      *(uint4*)(Ob + (size_t)(s0 + h*64 + s)*(size_t)N_TOK + l0 + col) = v;
    }
  }
}

__device__ __forceinline__ void proj_qk_body(
    char* lds, int bx, int which, int bb,
    const u16* __restrict__ xs_hi, const u16* __restrict__ ys_hi,
    const u16* __restrict__ Wqh, const u16* __restrict__ Wql,
    const u16* __restrict__ Wkh, const u16* __restrict__ Wkl,
    const float* __restrict__ bq, const float* __restrict__ bk,
    u16* __restrict__ Qout, u16* __restrict__ Kout)
{
  int branch = bb >> 2, batch = bb & 3;
  int n0 = bx * 256;
  const u16* Asrc = (which == 0 ? (branch ? ys_hi : xs_hi) : (branch ? xs_hi : ys_hi))
                    + (size_t)batch * N_TOK * C_DIM;
  const u16* Bh = which ? Wkh : Wqh;
  const u16* Bl = which ? Wkl : Wql;
  const float* bias = which ? bk : bq;
  float sc = which ? 1.0f : SCALE_Q2;   // Q pre-scaled into log2 domain
  u16* out = (which ? Kout : Qout) + (size_t)bb * N_TOK * DQK_;

  char* ldsA  = lds;
  char* ldsBh = lds + 32768;
  char* ldsBl = lds + 40960;

  int t = threadIdx.x, w = t >> 6, lane = t & 63, g = lane >> 5, l31 = lane & 31;
  int swz = (l31 & 7) << 4;

  f32x16 acc[2];
  #pragma unroll
  for (int i = 0; i < 2; ++i)
    #pragma unroll
    for (int r = 0; r < 16; ++r) acc[i][r] = 0.f;

  uint4 rA[8]; uint4 rBh, rBl;
  #pragma unroll
  for (int c = 0; c < 8; ++c) {
    int idx = c*256 + t, row = idx >> 3, slot = idx & 7;
    rA[c] = *(const uint4*)(Asrc + (size_t)(n0 + row)*C_DIM + slot*8);
  }
  { int row = t >> 3, slot = t & 7;
    rBh = *(const uint4*)(Bh + (size_t)row*C_DIM + slot*8);
    rBl = *(const uint4*)(Bl + (size_t)row*C_DIM + slot*8); }

  for (int bk = 0; bk < 4; ++bk) {
    __syncthreads();
    #pragma unroll
    for (int c = 0; c < 8; ++c) {
      int idx = c*256 + t, row = idx >> 3, slot = idx & 7;
      *(uint4*)(ldsA + row*128 + ((slot*16) ^ ((row & 7) << 4))) = rA[c];
    }
    { int row = t >> 3, slot = t & 7;
      int off = row*128 + ((slot*16) ^ ((row & 7) << 4));
      *(uint4*)(ldsBh + off) = rBh;
      *(uint4*)(ldsBl + off) = rBl; }
    __syncthreads();
    if (bk < 3) {
      #pragma unroll
      for (int c = 0; c < 8; ++c) {
        int idx = c*256 + t, row = idx >> 3, slot = idx & 7;
        rA[c] = *(const uint4*)(Asrc + (size_t)(n0 + row)*C_DIM + (bk+1)*64 + slot*8);
      }
      { int row = t >> 3, slot = t & 7;
        rBh = *(const uint4*)(Bh + (size_t)row*C_DIM + (bk+1)*64 + slot*8);
        rBl = *(const uint4*)(Bl + (size_t)row*C_DIM + (bk+1)*64 + slot*8); }
    }
    #pragma unroll
    for (int ks = 0; ks < 4; ++ks) {
      int ko = ks*32 + g*16;
      bf16x8 a0 = *(const bf16x8*)(ldsA + (w*64 + l31)*128      + (ko ^ swz));
      bf16x8 a1 = *(const bf16x8*)(ldsA + (w*64 + 32 + l31)*128 + (ko ^ swz));
      bf16x8 bh = *(const bf16x8*)(ldsBh + l31*128 + (ko ^ swz));
      bf16x8 bl = *(const bf16x8*)(ldsBl + l31*128 + (ko ^ swz));
      acc[0] = __builtin_amdgcn_mfma_f32_32x32x16_bf16(a0, bh, acc[0], 0,0,0);
      acc[1] = __builtin_amdgcn_mfma_f32_32x32x16_bf16(a1, bh, acc[1], 0,0,0);
      acc[0] = __builtin_amdgcn_mfma_f32_32x32x16_bf16(a0, bl, acc[0], 0,0,0);
      acc[1] = __builtin_amdgcn_mfma_f32_32x32x16_bf16(a1, bl, acc[1], 0,0,0);
    }
  }
  float bv = bias[l31];
  #pragma unroll
  for (int sub = 0; sub < 2; ++sub)
    #pragma unroll
    for (int r = 0; r < 16; ++r) {
      int n = w*64 + sub*32 + (r&3) + 8*(r>>2) + 4*g;
      out[(size_t)(n0 + n)*DQK_ + l31] = f2b((acc[sub][r] + bv) * sc);
    }
}

__global__ __launch_bounds__(256) void pv_qk_kernel(
    const u16* __restrict__ xs_hi, const u16* __restrict__ ys_hi,
    const u16* __restrict__ Wvh, const u16* __restrict__ Wvl,
    const u16* __restrict__ Wqh, const u16* __restrict__ Wql,
    const u16* __restrict__ Wkh, const u16* __restrict__ Wkl,
    const float* __restrict__ bv, const float* __restrict__ bq, const float* __restrict__ bk,
    u16* __restrict__ Vt, u16* __restrict__ Qout, u16* __restrict__ Kout)
{
  __shared__ __align__(16) char lds[49152];
  int bid = blockIdx.x;
  const size_t AS = (size_t)N_TOK * C_DIM;
  if (bid < 512) {
    int bx = bid & 31, by = (bid >> 5) & 1, bb = bid >> 6;
    gemm_v_body(lds, bx, by, bb, ys_hi, xs_hi, AS, Wvh, Wvl, bv, Vt, AS);
  } else {
    int pb = bid - 512;
    int bx = pb & 15, which = (pb >> 4) & 1, bb = pb >> 5;
    proj_qk_body(lds, bx, which, bb, xs_hi, ys_hi, Wqh, Wql, Wkh, Wkl, bq, bk, Qout, Kout);
  }
}

// ---------------- fused attn + FFN: one block = 128 q-rows of one bb ----------------
// Scores arrive in log2 domain (Q pre-scaled by log2e): P = exp2(S), one v_exp each.
__global__ __launch_bounds__(512) void attn_ffn_kernel(
    const u16* __restrict__ Qg, const u16* __restrict__ Kg,
    const u16* __restrict__ Vtg,
    const u16* __restrict__ W1h, const u16* __restrict__ W1l,
    const u16* __restrict__ W2h, const u16* __restrict__ W2l,
    const float* __restrict__ b1, const float* __restrict__ b2,
    float* __restrict__ out, float* __restrict__ part)
{
  __shared__ __align__(16) char lds[147456];
  int id = blockIdx.x;
  int bb = id & 7;
  int n0 = (id >> 3) * 128;
  const u16* Qb = Qg + (size_t)bb * N_TOK * DQK_;
  const u16* Kb = Kg + (size_t)bb * N_TOK * DQK_;
  const u16* Vb = Vtg + (size_t)bb * C_DIM * N_TOK;

  u16* Kl = (u16*)lds;                 // [grp][buf][2048]
  u16* Vl = (u16*)(lds + 16384);       // [grp][256*128]

  int t = threadIdx.x;
  int w = t >> 6;
  int grp = w >> 2;
  int wg = w & 3;
  int t4 = t & 255;
  int lane = t & 63, g = lane >> 5, l31 = lane & 31;
  int swz = (l31 & 7) << 4;

  bf16x8 qf0 = *(const bf16x8*)(Qb + (size_t)(n0 + wg*32 + l31)*DQK_ + g*8);
  bf16x8 qf1 = *(const bf16x8*)(Qb + (size_t)(n0 + wg*32 + l31)*DQK_ + 16 + g*8);

  f32x16 acc[8];
  #pragma unroll
  for (int ct = 0; ct < 8; ++ct)
    #pragma unroll
    for (int r = 0; r < 16; ++r) acc[ct][r] = 0.f;

  float L = 0.f;

  bf16x8 stK, stV[8];
  const u16* kSrc = Kb + (size_t)(grp*32*64 + (t4>>7)*32 + (t4&31))*DQK_
                       + ((t4>>6)&1)*16 + ((t4>>5)&1)*8;
  const int vCol0 = grp*32*64;
  stK = *(const bf16x8*)(kSrc);
  #pragma unroll
  for (int i = 0; i < 8; ++i) {
    int q = i*256 + t4;
    stV[i] = *(const bf16x8*)(Vb + (size_t)(q >> 3)*N_TOK + vCol0 + (q & 7)*8);
  }

  u16* VlG = Vl + grp*32768;

  *(bf16x8*)(Kl + grp*4096 + t4*8) = stK;
  #pragma unroll
  for (int i = 0; i < 8; ++i) {
    int q = i*256 + t4;
    int c = q >> 3, slot = q & 7;
    *(bf16x8*)((char*)VlG + c*256 + ((slot*16) ^ ((c & 15) << 4))) = stV[i];
  }
  __syncthreads();

  int h = 0;
  for (int mt = 0; mt < 32; ++mt) {
    const u16* KlG = Kl + grp*4096 + h*2048;
    f32x16 z;
    #pragma unroll
    for (int r = 0; r < 16; ++r) z[r] = 0.f;
    bf16x8 ka = *(const bf16x8*)(KlG + (0*64 + lane)*8);
    bf16x8 kb = *(const bf16x8*)(KlG + (1*64 + lane)*8);
    bf16x8 kc = *(const bf16x8*)(KlG + (2*64 + lane)*8);
    bf16x8 kd = *(const bf16x8*)(KlG + (3*64 + lane)*8);
    f32x16 st0 = __builtin_amdgcn_mfma_f32_32x32x16_bf16(ka, qf0, z, 0,0,0);
    st0 = __builtin_amdgcn_mfma_f32_32x32x16_bf16(kb, qf1, st0, 0,0,0);
    f32x16 st1 = __builtin_amdgcn_mfma_f32_32x32x16_bf16(kc, qf0, z, 0,0,0);
    st1 = __builtin_amdgcn_mfma_f32_32x32x16_bf16(kd, qf1, st1, 0,0,0);

    if (mt + 1 < 32) {
      stK = *(const bf16x8*)(kSrc + (size_t)(mt+1)*64*DQK_);
      #pragma unroll
      for (int i = 0; i < 8; ++i) {
        int q = i*256 + t4;
        stV[i] = *(const bf16x8*)(Vb + (size_t)(q >> 3)*N_TOK + vCol0 + (mt+1)*64 + (q & 7)*8);
      }
    }

    float ps = 0.f;
    uint4 pav[4];
    #pragma unroll
    for (int msub = 0; msub < 2; ++msub) {
      f32x16 sv = msub ? st1 : st0;
      float p[16];
      #pragma unroll
      for (int r = 0; r < 16; ++r)
        p[r] = exp2f(fminf(sv[r], 43.f));   // scores are log2-domain
      float q0 = (p[0]+p[1]) + (p[2]+p[3]);
      float q1 = (p[4]+p[5]) + (p[6]+p[7]);
      float q2 = (p[8]+p[9]) + (p[10]+p[11]);
      float q3 = (p[12]+p[13]) + (p[14]+p[15]);
      ps += (q0+q1) + (q2+q3);
      unsigned k0a = cvtpk(p[0],  p[1]),  k0b = cvtpk(p[2],  p[3]);
      unsigned k1a = cvtpk(p[4],  p[5]),  k1b = cvtpk(p[6],  p[7]);
      unsigned k2a = cvtpk(p[8],  p[9]),  k2b = cvtpk(p[10], p[11]);
      unsigned k3a = cvtpk(p[12], p[13]), k3b = cvtpk(p[14], p[15]);
      unsigned X1a = g ? k0a : k1a, X1b = g ? k0b : k1b;
      unsigned X2a = g ? k2a : k3a, X2b = g ? k2b : k3b;
      X1a = __shfl_xor(X1a, 32); X1b = __shfl_xor(X1b, 32);
      X2a = __shfl_xor(X2a, 32); X2b = __shfl_xor(X2b, 32);
      pav[msub*2]     = g ? make_uint4(X1a, X1b, k1a, k1b)
                          : make_uint4(k0a, k0b, X1a, X1b);
      pav[msub*2 + 1] = g ? make_uint4(X2a, X2b, k3a, k3b)
                          : make_uint4(k2a, k2b, X2a, X2b);
    }
    ps += __shfl_xor(ps, 32);
    L += ps;

    __builtin_amdgcn_s_setprio(1);
    #pragma unroll
    for (int ks = 0; ks < 4; ++ks) {
      bf16x8 pa = __builtin_bit_cast(bf16x8, pav[ks]);
      #pragma unroll
      for (int ct = 0; ct < 8; ++ct) {
        bf16x8 vv = *(const bf16x8*)((char*)VlG + (ct*32 + l31)*256
                     + ((h*128 + ks*32 + g*16) ^ ((l31 & 15) << 4)));
        acc[ct] = __builtin_amdgcn_mfma_f32_32x32x16_bf16(pa, vv, acc[ct], 0,0,0);
      }
    }
    __builtin_amdgcn_s_setprio(0);

    if (mt + 1 < 32) {
      *(bf16x8*)(Kl + grp*4096 + (h^1)*2048 + t4*8) = stK;
      #pragma unroll
      for (int i = 0; i < 8; ++i) {
        int q = i*256 + t4;
        int c = q >> 3, slot = q & 7;
        *(bf16x8*)((char*)VlG + c*256 + (((h ^ 1)*128 + slot*16) ^ ((c & 15) << 4))) = stV[i];
      }
    }
    __syncthreads();
    h ^= 1;
  }

  // merge grp1 -> grp0 (exact sums)
  float* mb = (float*)Kl;
  mb[t] = L;
  __syncthreads();
  float Ln = L + mb[t ^ 256];

  float* vb = (float*)Vl;
  #pragma unroll
  for (int pass = 0; pass < 2; ++pass) {
    __syncthreads();
    if (grp == 1) {
      #pragma unroll
      for (int cc = 0; cc < 4; ++cc) {
        int ct = pass*4 + cc;
        #pragma unroll
        for (int r = 0; r < 16; ++r)
          vb[(cc*256 + t4)*16 + r] = acc[ct][r];
      }
    }
    __syncthreads();
    if (grp == 0) {
      #pragma unroll
      for (int cc = 0; cc < 4; ++cc) {
        int ct = pass*4 + cc;
        #pragma unroll
        for (int r = 0; r < 16; ++r)
          acc[ct][r] += vb[(cc*256 + t4)*16 + r];
      }
    }
  }
  __syncthreads();   // vb reads done; O region may now be overwritten

  // grp0: normalized O -> LDS (bf16, [128][512B] XOR layout)
  char* ldsO = lds + 16384;
  if (grp == 0) {
    float lr = 1.0f / Ln;
    float lrr[16];
    #pragma unroll
    for (int r = 0; r < 16; ++r)
      lrr[r] = __shfl(lr, (r&3) + 8*(r>>2) + 4*g, 32);
    #pragma unroll
    for (int ct = 0; ct < 8; ++ct) {
      #pragma unroll
      for (int r = 0; r < 16; ++r) {
        int n = wg*32 + (r&3) + 8*(r>>2) + 4*g;
        int c = ct*32 + l31;
        *(u16*)(ldsO + n*512 + ((c*2) ^ ((n & 7) << 4))) = f2b(acc[ct][r] * lr);
      }
    }
  }
  __syncthreads();

  // ---------------- FFN ----------------
  int lw = (w & 1) * 64, sw = (w >> 1) * 64;
  char* ldsH1  = lds + 81920;
  char* ldsBh1 = lds + 81920;    // phase-1 W1 staging (dead before H1 write)
  char* ldsBl1 = lds + 114688;
  char* ldsBh2 = lds + 16384;    // phase-2 W2 staging (O region, dead)
  char* ldsBl2 = lds + 49152;

  f32x16 fa[2][2];
  #pragma unroll
  for (int i = 0; i < 2; ++i)
    #pragma unroll
    for (int j = 0; j < 2; ++j)
      #pragma unroll
      for (int r = 0; r < 16; ++r) fa[i][j][r] = 0.f;

  // phase 1: H1 = relu(O @ W1^T + b1)
  uint4 rBh[4], rBl[4];
  #pragma unroll
  for (int c = 0; c < 4; ++c) {
    int u = c*512 + t, row = u >> 3, slot = u & 7;
    rBh[c] = *(const uint4*)(W1h + (size_t)row*C_DIM + slot*8);
    rBl[c] = *(const uint4*)(W1l + (size_t)row*C_DIM + slot*8);
  }
  for (int bk = 0; bk < 4; ++bk) {
    __syncthreads();
    #pragma unroll
    for (int c = 0; c < 4; ++c) {
      int u = c*512 + t, row = u >> 3, slot = u & 7;
      int off = row*128 + ((slot*16) ^ ((row & 7) << 4));
      *(uint4*)(ldsBh1 + off) = rBh[c];
      *(uint4*)(ldsBl1 + off) = rBl[c];
    }
    __syncthreads();
    if (bk < 3) {
      #pragma unroll
      for (int c = 0; c < 4; ++c) {
        int u = c*512 + t, row = u >> 3, slot = u & 7;
        rBh[c] = *(const uint4*)(W1h + (size_t)row*C_DIM + (bk+1)*64 + slot*8);
        rBl[c] = *(const uint4*)(W1l + (size_t)row*C_DIM + (bk+1)*64 + slot*8);
      }
    }
    #pragma unroll
    for (int ks = 0; ks < 4; ++ks) {
      int ko = ks*32 + g*16;
      int kb = bk*128 + ko;
      bf16x8 ah0 = *(const bf16x8*)(ldsO + (lw + l31)*512      + (kb ^ swz));
      bf16x8 ah1 = *(const bf16x8*)(ldsO + (lw + 32 + l31)*512 + (kb ^ swz));
      bf16x8 bh0 = *(const bf16x8*)(ldsBh1 + (sw + l31)*128      + (ko ^ swz));
      bf16x8 bh1 = *(const bf16x8*)(ldsBh1 + (sw + 32 + l31)*128 + (ko ^ swz));
      bf16x8 bl0 = *(const bf16x8*)(ldsBl1 + (sw + l31)*128      + (ko ^ swz));
      bf16x8 bl1 = *(const bf16x8*)(ldsBl1 + (sw + 32 + l31)*128 + (ko ^ swz));
      fa[0][0] = __builtin_amdgcn_mfma_f32_32x32x16_bf16(ah0, bh0, fa[0][0], 0,0,0);
      fa[0][1] = __builtin_amdgcn_mfma_f32_32x32x16_bf16(ah0, bh1, fa[0][1], 0,0,0);
      fa[1][0] = __builtin_amdgcn_mfma_f32_32x32x16_bf16(ah1, bh0, fa[1][0], 0,0,0);
      fa[1][1] = __builtin_amdgcn_mfma_f32_32x32x16_bf16(ah1, bh1, fa[1][1], 0,0,0);
      fa[0][0] = __builtin_amdgcn_mfma_f32_32x32x16_bf16(ah0, bl0, fa[0][0], 0,0,0);
      fa[0][1] = __builtin_amdgcn_mfma_f32_32x32x16_bf16(ah0, bl1, fa[0][1], 0,0,0);
      fa[1][0] = __builtin_amdgcn_mfma_f32_32x32x16_bf16(ah1, bl0, fa[1][0], 0,0,0);
      fa[1][1] = __builtin_amdgcn_mfma_f32_32x32x16_bf16(ah1, bl1, fa[1][1], 0,0,0);
    }
  }
  __syncthreads();   // W1 staging reads done; region becomes H1

  #pragma unroll
  for (int j = 0; j < 2; ++j) {
    int o = sw + j*32 + l31;
    float bvv = b1[o];
    #pragma unroll
    for (int i = 0; i < 2; ++i)
      #pragma unroll
      for (int r = 0; r < 16; ++r) {
        int n = lw + i*32 + (r&3) + 8*(r>>2) + 4*g;
        *(u16*)(ldsH1 + n*512 + ((o*2) ^ ((n & 7) << 4))) = f2b(fmaxf(fa[i][j][r] + bvv, 0.f));
      }
  }

  #pragma unroll
  for (int i = 0; i < 2; ++i)
    #pragma unroll
    for (int j = 0; j < 2; ++j)
      #pragma unroll
      for (int r = 0; r < 16; ++r) fa[i][j][r] = 0.f;

  // phase 2: out = H1 @ W2^T + b2
  #pragma unroll
  for (int c = 0; c < 4; ++c) {
    int u = c*512 + t, row = u >> 3, slot = u & 7;
    rBh[c] = *(const uint4*)(W2h + (size_t)row*C_DIM + slot*8);
    rBl[c] = *(const uint4*)(W2l + (size_t)row*C_DIM + slot*8);
  }
  for (int bk = 0; bk < 4; ++bk) {
    __syncthreads();   // first iter: H1 writes visible
    #pragma unroll
    for (int c = 0; c < 4; ++c) {
      int u = c*512 + t, row = u >> 3, slot = u & 7;
      int off = row*128 + ((slot*16) ^ ((row & 7) << 4));
      *(uint4*)(ldsBh2 + off) = rBh[c];
      *(uint4*)(ldsBl2 + off) = rBl[c];
    }
    __syncthreads();
    if (bk < 3) {
      #pragma unroll
      for (int c = 0; c < 4; ++c) {
        int u = c*512 + t, row = u >> 3, slot = u & 7;
        rBh[c] = *(const uint4*)(W2h + (size_t)row*C_DIM + (bk+1)*64 + slot*8);
        rBl[c] = *(const uint4*)(W2l + (size_t)row*C_DIM + (bk+1)*64 + slot*8);
      }
    }
    #pragma unroll
    for (int ks = 0; ks < 4; ++ks) {
      int ko = ks*32 + g*16;
      int kb = bk*128 + ko;
      bf16x8 ah0 = *(const bf16x8*)(ldsH1 + (lw + l31)*512      + (kb ^ swz));
      bf16x8 ah1 = *(const bf16x8*)(ldsH1 + (lw + 32 + l31)*512 + (kb ^ swz));
      bf16x8 bh0 = *(const bf16x8*)(ldsBh2 + (sw + l31)*128      + (ko ^ swz));
      bf16x8 bh1 = *(const bf16x8*)(ldsBh2 + (sw + 32 + l31)*128 + (ko ^ swz));
      bf16x8 bl0 = *(const bf16x8*)(ldsBl2 + (sw + l31)*128      + (ko ^ swz));
      bf16x8 bl1 = *(const bf16x8*)(ldsBl2 + (sw + 32 + l31)*128 + (ko ^ swz));
      fa[0][0] = __builtin_amdgcn_mfma_f32_32x32x16_bf16(ah0, bh0, fa[0][0], 0,0,0);
      fa[0][1] = __builtin_amdgcn_mfma_f32_32x32x16_bf16(ah0, bh1, fa[0][1], 0,0,0);
      fa[1][0] = __builtin_amdgcn_mfma_f32_32x32x16_bf16(ah1, bh0, fa[1][0], 0,0,0);
      fa[1][1] = __builtin_amdgcn_mfma_f32_32x32x16_bf16(ah1, bh1, fa[1][1], 0,0,0);
      fa[0][0] = __builtin_amdgcn_mfma_f32_32x32x16_bf16(ah0, bl0, fa[0][0], 0,0,0);
      fa[0][1] = __builtin_amdgcn_mfma_f32_32x32x16_bf16(ah0, bl1, fa[0][1], 0,0,0);
      fa[1][0] = __builtin_amdgcn_mfma_f32_32x32x16_bf16(ah1, bl0, fa[1][0], 0,0,0);
      fa[1][1] = __builtin_amdgcn_mfma_f32_32x32x16_bf16(ah1, bl1, fa[1][1], 0,0,0);
    }
  }

  // bias + LN partial sums
  float s = 0.f, s2 = 0.f;
  #pragma unroll
  for (int j = 0; j < 2; ++j) {
    float bvv = b2[sw + j*32 + l31];
    #pragma unroll
    for (int i = 0; i < 2; ++i)
      #pragma unroll
      for (int r = 0; r < 16; ++r) {
        fa[i][j][r] += bvv;
        s += fa[i][j][r];
        s2 += fa[i][j][r]*fa[i][j][r];
      }
  }
  for (int off = 32; off; off >>= 1) {
    s  += __shfl_down(s, off, 64);
    s2 += __shfl_down(s2, off, 64);
  }
  __syncthreads();
  float* sc = (float*)lds;   // Kl region, dead
  if (lane == 0) { sc[w*2] = s; sc[w*2+1] = s2; }
  __syncthreads();
  if (t == 0) {
    int slot = bb*32 + (id >> 3);
    float S = 0.f, S2 = 0.f;
    #pragma unroll
    for (int q = 0; q < 8; ++q) { S += sc[q*2]; S2 += sc[q*2+1]; }
    part[slot*2]     = S;
    part[slot*2 + 1] = S2;
  }

  // transposed f32 store via LDS: 4 quarter-passes (64 short rows each) in O region
  float* Ob = out + (size_t)bb * (size_t)N_TOK * C_DIM;   // [c][n]
  int l0 = n0;
  for (int qp = 0; qp < 4; ++qp) {
    __syncthreads();
    if ((w >> 1) == qp) {
      #pragma unroll
      for (int j = 0; j < 2; ++j) {
        int sl = j*32 + l31;                 // 0..63 within quarter
        #pragma unroll
        for (int i = 0; i < 2; ++i)
          #pragma unroll
          for (int q = 0; q < 4; ++q) {
            int lbase = lw + i*32 + 8*q + 4*g;
            float4 vv;
            vv.x = fa[i][j][q*4+0];
            vv.y = fa[i][j][q*4+1];
            vv.z = fa[i][j][q*4+2];
            vv.w = fa[i][j][q*4+3];
            *(float4*)(ldsO + sl*528 + lbase*4) = vv;
          }
      }
    }
    __syncthreads();
    #pragma unroll
    for (int p2 = 0; p2 < 4; ++p2) {
      int idx = p2*512 + t;
      int sl = idx >> 5, col = (idx & 31)*4;
      float4 v = *(const float4*)(ldsO + sl*528 + col*4);
      *(float4*)(Ob + (size_t)(qp*64 + sl)*(size_t)N_TOK + l0 + col) = v;
    }
  }
}

// ---------------- ln_apply with inline stats reduce ----------------
__global__ __launch_bounds__(256) void ln_apply_kernel(
    float* __restrict__ H, const float* __restrict__ gamma,
    const float* __restrict__ beta, const float* __restrict__ part)
{
  __shared__ float st[2];
  int base = blockIdx.x * 4096;
  int bb = base >> 20;
  int t = threadIdx.x;
  if (t < 64) {
    float s = 0.f, s2 = 0.f;
    if (t < 32) { s = part[(bb*32 + t)*2]; s2 = part[(bb*32 + t)*2 + 1]; }
    for (int off = 16; off; off >>= 1) {
      s  += __shfl_down(s, off, 64);
      s2 += __shfl_down(s2, off, 64);
    }
    if (t == 0) {
      float mean = s * (1.0f/1048576.0f);
      float var  = s2 * (1.0f/1048576.0f) - mean*mean;
      st[0] = mean;
      st[1] = rsqrtf(var + 1e-5f);
    }
  }
  __syncthreads();
  float mean = st[0], istd = st[1];
  #pragma unroll
  for (int k = 0; k < 4; ++k) {
    int e = base + (k*256 + t)*4;
    int rem = e & ((1 << 20) - 1);
    float4 h = *(float4*)(H + (size_t)e);
    float4 g = *(const float4*)(gamma + rem);
    float4 b = *(const float4*)(beta + rem);
    h.x = (h.x - mean)*istd*g.x + b.x;
    h.y = (h.y - mean)*istd*g.y + b.y;
    h.z = (h.z - mean)*istd*g.z + b.z;
    h.w = (h.w - mean)*istd*g.w + b.w;
    *(float4*)(H + (size_t)e) = h;
  }
}

extern "C" void kernel_launch(void* const* d_in, const int* in_sizes, int n_in,
                              void* d_out, int out_size, void* d_ws, size_t ws_size,
                              hipStream_t stream) {
  (void)in_sizes; (void)n_in; (void)out_size; (void)ws_size;
  const float* x  = (const float*)d_in[0];
  const float* y  = (const float*)d_in[1];
  const float* Wq = (const float*)d_in[2];
  const float* bq = (const float*)d_in[3];
  const float* Wk = (const float*)d_in[4];
  const float* bk = (const float*)d_in[5];
  const float* Wv = (const float*)d_in[6];
  const float* bv = (const float*)d_in[7];
  const float* W1 = (const float*)d_in[8];
  const float* b1 = (const float*)d_in[9];
  const float* W2 = (const float*)d_in[10];
  const float* b2 = (const float*)d_in[11];
  const float* gamma = (const float*)d_in[12];
  const float* beta  = (const float*)d_in[13];
  float* out = (float*)d_out;

  char* ws = (char*)d_ws;
  u16* xs_hi = (u16*)(ws);
  u16* ys_hi = (u16*)(ws + (8ull<<20));
  u16* Q     = (u16*)(ws + (16ull<<20));
  u16* Kp    = (u16*)(ws + (18ull<<20));
  u16* Vt    = (u16*)(ws + (20ull<<20));
  u16* Wvh   = (u16*)(ws + (52ull<<20));
  u16* Wvl   = Wvh + 65536;
  u16* W1h   = Wvh + 2*65536;
  u16* W1l   = Wvh + 3*65536;
  u16* W2h   = Wvh + 4*65536;
  u16* W2l   = Wvh + 5*65536;
  u16* Wqh   = Wvh + 6*65536;
  u16* Wql   = Wqh + 8192;
  u16* Wkh   = Wqh + 2*8192;
  u16* Wkl   = Wqh + 3*8192;
  float* part  = (float*)(ws + (53ull<<20));

  prep_kernel <<<2880, 256, 0, stream>>>(
      x, y, xs_hi, ys_hi, Wv, W1, W2, Wq, Wk,
      Wvh, Wvl, W1h, W1l, W2h, W2l, Wqh, Wql, Wkh, Wkl);
  pv_qk_kernel<<<768, 256, 0, stream>>>(
      xs_hi, ys_hi, Wvh, Wvl, Wqh, Wql, Wkh, Wkl, bv, bq, bk, Vt, Q, Kp);
  attn_ffn_kernel<<<256, 512, 0, stream>>>(
      Q, Kp, Vt, W1h, W1l, W2h, W2l, b1, b2, out, part);
  ln_apply_kernel <<<2048, 256, 0, stream>>>(out, gamma, beta, part);
}

// Round 17
// 216.307 us; speedup vs baseline: 1.0507x; 1.0507x over previous
//
#include <hip/hip_runtime.h>

#define C_DIM 256
#define N_TOK 4096
#define DQK_  32
#define SCALE_Q2 0.25504345023688654f  // 1/sqrt(32) * log2(e): scores in log2 domain

typedef unsigned short u16;
typedef __attribute__((ext_vector_type(8))) short bf16x8;
typedef __attribute__((ext_vector_type(16))) float f32x16;

__device__ __forceinline__ u16 f2b(float f) {
  unsigned u = __builtin_bit_cast(unsigned, f);
  unsigned r = (u + 0x7fffu + ((u >> 16) & 1u)) >> 16;
  return (u16)r;
}
__device__ __forceinline__ unsigned splitw(float v) {
  unsigned h = f2b(v);
  float hf = __builtin_bit_cast(float, h << 16);
  unsigned l = f2b(v - hf);
  return h | (l << 16);
}
__device__ __forceinline__ unsigned cvtpk(float lo, float hi) {
  unsigned r;
  asm("v_cvt_pk_bf16_f32 %0, %1, %2" : "=v"(r) : "v"(lo), "v"(hi));
  return r;
}
// bare v_exp_f32 (2^x). Builtin preferred (backend handles trans-use hazard);
// asm fallback includes s_nop 0 for the hazard.
__device__ __forceinline__ float fexp2(float x) {
#if __has_builtin(__builtin_amdgcn_exp2f)
  return __builtin_amdgcn_exp2f(x);
#else
  float r;
  asm volatile("v_exp_f32 %0, %1\n\ts_nop 0" : "=v"(r) : "v"(x));
  return r;
#endif
}

// ---------------- prep: act transpose->bf16 planes + weight split planes ----------------
__global__ __launch_bounds__(256) void prep_kernel(
    const float* __restrict__ x, const float* __restrict__ y,
    u16* __restrict__ xhi, u16* __restrict__ yhi,
    const float* __restrict__ Wv, const float* __restrict__ W1, const float* __restrict__ W2,
    const float* __restrict__ Wq, const float* __restrict__ Wk,
    u16* __restrict__ Wvh, u16* __restrict__ Wvl,
    u16* __restrict__ W1h, u16* __restrict__ W1l,
    u16* __restrict__ W2h, u16* __restrict__ W2l,
    u16* __restrict__ Wqh, u16* __restrict__ Wql,
    u16* __restrict__ Wkh, u16* __restrict__ Wkl)
{
  __shared__ float tile[64][65];
  int bid = blockIdx.x;
  int t = threadIdx.x;
  if (bid < 2048) {
    int bx = bid & 63, by = (bid >> 6) & 3, z = bid >> 8;
    const float* src = (z < 4 ? x : y) + (size_t)(z & 3) * C_DIM * N_TOK;
    u16* dhi = (z < 4 ? xhi : yhi) + (size_t)(z & 3) * N_TOK * C_DIM;
    int m0 = bx * 64, c0 = by * 64;
    #pragma unroll
    for (int pp = 0; pp < 4; ++pp) {
      int c = pp*16 + (t >> 4), m = (t & 15)*4;
      float4 v = *(const float4*)(src + (size_t)(c0 + c)*N_TOK + m0 + m);
      tile[c][m] = v.x; tile[c][m+1] = v.y; tile[c][m+2] = v.z; tile[c][m+3] = v.w;
    }
    __syncthreads();
    int m = t >> 2, cg = (t & 3) * 16;
    unsigned hw[8];
    #pragma unroll
    for (int j2 = 0; j2 < 8; ++j2)
      hw[j2] = (unsigned)f2b(tile[cg + 2*j2][m]) | ((unsigned)f2b(tile[cg + 2*j2 + 1][m]) << 16);
    size_t base = (size_t)(m0 + m)*C_DIM + c0 + cg;
    *(uint4*)(dhi + base)     = make_uint4(hw[0], hw[1], hw[2], hw[3]);
    *(uint4*)(dhi + base + 8) = make_uint4(hw[4], hw[5], hw[6], hw[7]);
  } else {
    int wb = bid - 2048;
    int which, base;
    if (wb < 768) { which = wb >> 8; base = wb & 255; }
    else if (wb < 800) { which = 3; base = wb - 768; }
    else { which = 4; base = wb - 800; }
    const float* src = which == 0 ? Wv : which == 1 ? W1 : which == 2 ? W2 : which == 3 ? Wq : Wk;
    u16* dhi = which == 0 ? Wvh : which == 1 ? W1h : which == 2 ? W2h : which == 3 ? Wqh : Wkh;
    u16* dlo = which == 0 ? Wvl : which == 1 ? W1l : which == 2 ? W2l : which == 3 ? Wql : Wkl;
    int idx = base*256 + t;
    unsigned s = splitw(src[idx]);
    dhi[idx] = (u16)(s & 0xffffu);
    dlo[idx] = (u16)(s >> 16);
  }
}

// ---------------- bodies for the fused proj_v / proj_qk launch ----------------
__device__ __forceinline__ void gemm_v_body(
    char* lds, int bx, int by, int bb,
    const u16* __restrict__ Ahi0, const u16* __restrict__ Ahi1, size_t aStride,
    const u16* __restrict__ Bhi, const u16* __restrict__ Blo,
    const float* __restrict__ bias, u16* __restrict__ OutBase, size_t oStride)
{
  const u16* Ah = (bb < 4 ? Ahi0 : Ahi1) + (size_t)(bb & 3) * aStride;
  int l0 = bx * 128;
  int s0 = by * 128;
  u16* Ob = OutBase + (size_t)bb * oStride;

  char* ldsAh = lds;
  char* ldsBh = lds + 16384;
  char* ldsBl = lds + 32768;

  int t = threadIdx.x;
  int w = t >> 6, lane = t & 63, g = lane >> 5, l31 = lane & 31;
  int lw = (w & 1) * 64, sw = (w >> 1) * 64;
  int swz = (l31 & 7) << 4;

  f32x16 acc[2][2];
  #pragma unroll
  for (int i = 0; i < 2; ++i)
    #pragma unroll
    for (int j = 0; j < 2; ++j)
      #pragma unroll
      for (int r = 0; r < 16; ++r) acc[i][j][r] = 0.f;

  uint4 rAh[4], rBh[4], rBl[4];
  #pragma unroll
  for (int c = 0; c < 4; ++c) {
    int idx = c*256 + t, row = idx >> 3, slot = idx & 7;
    rAh[c] = *(const uint4*)(Ah  + (size_t)(l0 + row)*C_DIM + slot*8);
    rBh[c] = *(const uint4*)(Bhi + (size_t)(s0 + row)*C_DIM + slot*8);
    rBl[c] = *(const uint4*)(Blo + (size_t)(s0 + row)*C_DIM + slot*8);
  }
  for (int bk = 0; bk < 4; ++bk) {
    __syncthreads();
    #pragma unroll
    for (int c = 0; c < 4; ++c) {
      int idx = c*256 + t, row = idx >> 3, slot = idx & 7;
      int off = row*128 + ((slot*16) ^ ((row & 7) << 4));
      *(uint4*)(ldsAh + off) = rAh[c];
      *(uint4*)(ldsBh + off) = rBh[c];
      *(uint4*)(ldsBl + off) = rBl[c];
    }
    __syncthreads();
    if (bk < 3) {
      #pragma unroll
      for (int c = 0; c < 4; ++c) {
        int idx = c*256 + t, row = idx >> 3, slot = idx & 7;
        rAh[c] = *(const uint4*)(Ah  + (size_t)(l0 + row)*C_DIM + (bk+1)*64 + slot*8);
        rBh[c] = *(const uint4*)(Bhi + (size_t)(s0 + row)*C_DIM + (bk+1)*64 + slot*8);
        rBl[c] = *(const uint4*)(Blo + (size_t)(s0 + row)*C_DIM + (bk+1)*64 + slot*8);
      }
    }
    #pragma unroll
    for (int ks = 0; ks < 4; ++ks) {
      int ko = ks*32 + g*16;
      bf16x8 ah0 = *(const bf16x8*)(ldsAh + (lw + l31)*128      + (ko ^ swz));
      bf16x8 ah1 = *(const bf16x8*)(ldsAh + (lw + 32 + l31)*128 + (ko ^ swz));
      bf16x8 bh0 = *(const bf16x8*)(ldsBh + (sw + l31)*128      + (ko ^ swz));
      bf16x8 bh1 = *(const bf16x8*)(ldsBh + (sw + 32 + l31)*128 + (ko ^ swz));
      bf16x8 bl0 = *(const bf16x8*)(ldsBl + (sw + l31)*128      + (ko ^ swz));
      bf16x8 bl1 = *(const bf16x8*)(ldsBl + (sw + 32 + l31)*128 + (ko ^ swz));
      acc[0][0] = __builtin_amdgcn_mfma_f32_32x32x16_bf16(ah0, bh0, acc[0][0], 0,0,0);
      acc[0][1] = __builtin_amdgcn_mfma_f32_32x32x16_bf16(ah0, bh1, acc[0][1], 0,0,0);
      acc[1][0] = __builtin_amdgcn_mfma_f32_32x32x16_bf16(ah1, bh0, acc[1][0], 0,0,0);
      acc[1][1] = __builtin_amdgcn_mfma_f32_32x32x16_bf16(ah1, bh1, acc[1][1], 0,0,0);
      acc[0][0] = __builtin_amdgcn_mfma_f32_32x32x16_bf16(ah0, bl0, acc[0][0], 0,0,0);
      acc[0][1] = __builtin_amdgcn_mfma_f32_32x32x16_bf16(ah0, bl1, acc[0][1], 0,0,0);
      acc[1][0] = __builtin_amdgcn_mfma_f32_32x32x16_bf16(ah1, bl0, acc[1][0], 0,0,0);
      acc[1][1] = __builtin_amdgcn_mfma_f32_32x32x16_bf16(ah1, bl1, acc[1][1], 0,0,0);
    }
  }

  for (int h = 0; h < 2; ++h) {
    __syncthreads();
    if ((w >> 1) == h) {
      #pragma unroll
      for (int j = 0; j < 2; ++j) {
        int sl = j*32 + l31;
        float bv = bias[s0 + h*64 + sl];
        #pragma unroll
        for (int i = 0; i < 2; ++i)
          #pragma unroll
          for (int q = 0; q < 4; ++q) {
            int lbase = lw + i*32 + 8*q + 4*g;
            unsigned w0 = (unsigned)f2b(acc[i][j][q*4+0] + bv)
                        | ((unsigned)f2b(acc[i][j][q*4+1] + bv) << 16);
            unsigned w1 = (unsigned)f2b(acc[i][j][q*4+2] + bv)
                        | ((unsigned)f2b(acc[i][j][q*4+3] + bv) << 16);
            *(uint2*)(lds + sl*272 + lbase*2) = make_uint2(w0, w1);
          }
      }
    }
    __syncthreads();
    #pragma unroll
    for (int p = 0; p < 4; ++p) {
      int s = p*16 + (t >> 4), col = (t & 15)*8;
      uint4 v = *(const uint4*)(lds + s*272 + col*2);
      *(uint4*)(Ob + (size_t)(s0 + h*64 + s)*(size_t)N_TOK + l0 + col) = v;
    }
  }
}

__device__ __forceinline__ void proj_qk_body(
    char* lds, int bx, int which, int bb,
    const u16* __restrict__ xs_hi, const u16* __restrict__ ys_hi,
    const u16* __restrict__ Wqh, const u16* __restrict__ Wql,
    const u16* __restrict__ Wkh, const u16* __restrict__ Wkl,
    const float* __restrict__ bq, const float* __restrict__ bk,
    u16* __restrict__ Qout, u16* __restrict__ Kout)
{
  int branch = bb >> 2, batch = bb & 3;
  int n0 = bx * 256;
  const u16* Asrc = (which == 0 ? (branch ? ys_hi : xs_hi) : (branch ? xs_hi : ys_hi))
                    + (size_t)batch * N_TOK * C_DIM;
  const u16* Bh = which ? Wkh : Wqh;
  const u16* Bl = which ? Wkl : Wql;
  const float* bias = which ? bk : bq;
  float sc = which ? 1.0f : SCALE_Q2;   // Q pre-scaled into log2 domain
  u16* out = (which ? Kout : Qout) + (size_t)bb * N_TOK * DQK_;

  char* ldsA  = lds;
  char* ldsBh = lds + 32768;
  char* ldsBl = lds + 40960;

  int t = threadIdx.x, w = t >> 6, lane = t & 63, g = lane >> 5, l31 = lane & 31;
  int swz = (l31 & 7) << 4;

  f32x16 acc[2];
  #pragma unroll
  for (int i = 0; i < 2; ++i)
    #pragma unroll
    for (int r = 0; r < 16; ++r) acc[i][r] = 0.f;

  uint4 rA[8]; uint4 rBh, rBl;
  #pragma unroll
  for (int c = 0; c < 8; ++c) {
    int idx = c*256 + t, row = idx >> 3, slot = idx & 7;
    rA[c] = *(const uint4*)(Asrc + (size_t)(n0 + row)*C_DIM + slot*8);
  }
  { int row = t >> 3, slot = t & 7;
    rBh = *(const uint4*)(Bh + (size_t)row*C_DIM + slot*8);
    rBl = *(const uint4*)(Bl + (size_t)row*C_DIM + slot*8); }

  for (int bk = 0; bk < 4; ++bk) {
    __syncthreads();
    #pragma unroll
    for (int c = 0; c < 8; ++c) {
      int idx = c*256 + t, row = idx >> 3, slot = idx & 7;
      *(uint4*)(ldsA + row*128 + ((slot*16) ^ ((row & 7) << 4))) = rA[c];
    }
    { int row = t >> 3, slot = t & 7;
      int off = row*128 + ((slot*16) ^ ((row & 7) << 4));
      *(uint4*)(ldsBh + off) = rBh;
      *(uint4*)(ldsBl + off) = rBl; }
    __syncthreads();
    if (bk < 3) {
      #pragma unroll
      for (int c = 0; c < 8; ++c) {
        int idx = c*256 + t, row = idx >> 3, slot = idx & 7;
        rA[c] = *(const uint4*)(Asrc + (size_t)(n0 + row)*C_DIM + (bk+1)*64 + slot*8);
      }
      { int row = t >> 3, slot = t & 7;
        rBh = *(const uint4*)(Bh + (size_t)row*C_DIM + (bk+1)*64 + slot*8);
        rBl = *(const uint4*)(Bl + (size_t)row*C_DIM + (bk+1)*64 + slot*8); }
    }
    #pragma unroll
    for (int ks = 0; ks < 4; ++ks) {
      int ko = ks*32 + g*16;
      bf16x8 a0 = *(const bf16x8*)(ldsA + (w*64 + l31)*128      + (ko ^ swz));
      bf16x8 a1 = *(const bf16x8*)(ldsA + (w*64 + 32 + l31)*128 + (ko ^ swz));
      bf16x8 bh = *(const bf16x8*)(ldsBh + l31*128 + (ko ^ swz));
      bf16x8 bl = *(const bf16x8*)(ldsBl + l31*128 + (ko ^ swz));
      acc[0] = __builtin_amdgcn_mfma_f32_32x32x16_bf16(a0, bh, acc[0], 0,0,0);
      acc[1] = __builtin_amdgcn_mfma_f32_32x32x16_bf16(a1, bh, acc[1], 0,0,0);
      acc[0] = __builtin_amdgcn_mfma_f32_32x32x16_bf16(a0, bl, acc[0], 0,0,0);
      acc[1] = __builtin_amdgcn_mfma_f32_32x32x16_bf16(a1, bl, acc[1], 0,0,0);
    }
  }
  float bv = bias[l31];
  #pragma unroll
  for (int sub = 0; sub < 2; ++sub)
    #pragma unroll
    for (int r = 0; r < 16; ++r) {
      int n = w*64 + sub*32 + (r&3) + 8*(r>>2) + 4*g;
      out[(size_t)(n0 + n)*DQK_ + l31] = f2b((acc[sub][r] + bv) * sc);
    }
}

__global__ __launch_bounds__(256) void pv_qk_kernel(
    const u16* __restrict__ xs_hi, const u16* __restrict__ ys_hi,
    const u16* __restrict__ Wvh, const u16* __restrict__ Wvl,
    const u16* __restrict__ Wqh, const u16* __restrict__ Wql,
    const u16* __restrict__ Wkh, const u16* __restrict__ Wkl,
    const float* __restrict__ bv, const float* __restrict__ bq, const float* __restrict__ bk,
    u16* __restrict__ Vt, u16* __restrict__ Qout, u16* __restrict__ Kout)
{
  __shared__ __align__(16) char lds[49152];
  int bid = blockIdx.x;
  const size_t AS = (size_t)N_TOK * C_DIM;
  if (bid < 512) {
    int bx = bid & 31, by = (bid >> 5) & 1, bb = bid >> 6;
    gemm_v_body(lds, bx, by, bb, ys_hi, xs_hi, AS, Wvh, Wvl, bv, Vt, AS);
  } else {
    int pb = bid - 512;
    int bx = pb & 15, which = (pb >> 4) & 1, bb = pb >> 5;
    proj_qk_body(lds, bx, which, bb, xs_hi, ys_hi, Wqh, Wql, Wkh, Wkl, bq, bk, Qout, Kout);
  }
}

// ---------------- fused attn + FFN: one block = 128 q-rows of one bb ----------------
// Scores in log2 domain (Q pre-scaled by log2e): P = v_exp_f32(S) directly.
__global__ __launch_bounds__(512) void attn_ffn_kernel(
    const u16* __restrict__ Qg, const u16* __restrict__ Kg,
    const u16* __restrict__ Vtg,
    const u16* __restrict__ W1h, const u16* __restrict__ W1l,
    const u16* __restrict__ W2h, const u16* __restrict__ W2l,
    const float* __restrict__ b1, const float* __restrict__ b2,
    float* __restrict__ out, float* __restrict__ part)
{
  __shared__ __align__(16) char lds[147456];
  int id = blockIdx.x;
  int bb = id & 7;
  int n0 = (id >> 3) * 128;
  const u16* Qb = Qg + (size_t)bb * N_TOK * DQK_;
  const u16* Kb = Kg + (size_t)bb * N_TOK * DQK_;
  const u16* Vb = Vtg + (size_t)bb * C_DIM * N_TOK;

  u16* Kl = (u16*)lds;                 // [grp][buf][2048]
  u16* Vl = (u16*)(lds + 16384);       // [grp][256*128]

  int t = threadIdx.x;
  int w = t >> 6;
  int grp = w >> 2;
  int wg = w & 3;
  int t4 = t & 255;
  int lane = t & 63, g = lane >> 5, l31 = lane & 31;
  int swz = (l31 & 7) << 4;

  bf16x8 qf0 = *(const bf16x8*)(Qb + (size_t)(n0 + wg*32 + l31)*DQK_ + g*8);
  bf16x8 qf1 = *(const bf16x8*)(Qb + (size_t)(n0 + wg*32 + l31)*DQK_ + 16 + g*8);

  f32x16 acc[8];
  #pragma unroll
  for (int ct = 0; ct < 8; ++ct)
    #pragma unroll
    for (int r = 0; r < 16; ++r) acc[ct][r] = 0.f;

  float L = 0.f;

  bf16x8 stK, stV[8];
  const u16* kSrc = Kb + (size_t)(grp*32*64 + (t4>>7)*32 + (t4&31))*DQK_
                       + ((t4>>6)&1)*16 + ((t4>>5)&1)*8;
  const int vCol0 = grp*32*64;
  stK = *(const bf16x8*)(kSrc);
  #pragma unroll
  for (int i = 0; i < 8; ++i) {
    int q = i*256 + t4;
    stV[i] = *(const bf16x8*)(Vb + (size_t)(q >> 3)*N_TOK + vCol0 + (q & 7)*8);
  }

  u16* VlG = Vl + grp*32768;

  *(bf16x8*)(Kl + grp*4096 + t4*8) = stK;
  #pragma unroll
  for (int i = 0; i < 8; ++i) {
    int q = i*256 + t4;
    int c = q >> 3, slot = q & 7;
    *(bf16x8*)((char*)VlG + c*256 + ((slot*16) ^ ((c & 15) << 4))) = stV[i];
  }
  __syncthreads();

  int h = 0;
  for (int mt = 0; mt < 32; ++mt) {
    const u16* KlG = Kl + grp*4096 + h*2048;
    f32x16 z;
    #pragma unroll
    for (int r = 0; r < 16; ++r) z[r] = 0.f;
    bf16x8 ka = *(const bf16x8*)(KlG + (0*64 + lane)*8);
    bf16x8 kb = *(const bf16x8*)(KlG + (1*64 + lane)*8);
    bf16x8 kc = *(const bf16x8*)(KlG + (2*64 + lane)*8);
    bf16x8 kd = *(const bf16x8*)(KlG + (3*64 + lane)*8);
    f32x16 st0 = __builtin_amdgcn_mfma_f32_32x32x16_bf16(ka, qf0, z, 0,0,0);
    st0 = __builtin_amdgcn_mfma_f32_32x32x16_bf16(kb, qf1, st0, 0,0,0);
    f32x16 st1 = __builtin_amdgcn_mfma_f32_32x32x16_bf16(kc, qf0, z, 0,0,0);
    st1 = __builtin_amdgcn_mfma_f32_32x32x16_bf16(kd, qf1, st1, 0,0,0);

    if (mt + 1 < 32) {
      stK = *(const bf16x8*)(kSrc + (size_t)(mt+1)*64*DQK_);
      #pragma unroll
      for (int i = 0; i < 8; ++i) {
        int q = i*256 + t4;
        stV[i] = *(const bf16x8*)(Vb + (size_t)(q >> 3)*N_TOK + vCol0 + (mt+1)*64 + (q & 7)*8);
      }
    }

    float ps = 0.f;
    uint4 pav[4];
    #pragma unroll
    for (int msub = 0; msub < 2; ++msub) {
      f32x16 sv = msub ? st1 : st0;
      float p[16];
      #pragma unroll
      for (int r = 0; r < 16; ++r)
        p[r] = fexp2(fminf(sv[r], 43.f));   // scores are log2-domain
      float q0 = (p[0]+p[1]) + (p[2]+p[3]);
      float q1 = (p[4]+p[5]) + (p[6]+p[7]);
      float q2 = (p[8]+p[9]) + (p[10]+p[11]);
      float q3 = (p[12]+p[13]) + (p[14]+p[15]);
      ps += (q0+q1) + (q2+q3);
      unsigned k0a = cvtpk(p[0],  p[1]),  k0b = cvtpk(p[2],  p[3]);
      unsigned k1a = cvtpk(p[4],  p[5]),  k1b = cvtpk(p[6],  p[7]);
      unsigned k2a = cvtpk(p[8],  p[9]),  k2b = cvtpk(p[10], p[11]);
      unsigned k3a = cvtpk(p[12], p[13]), k3b = cvtpk(p[14], p[15]);
      unsigned X1a = g ? k0a : k1a, X1b = g ? k0b : k1b;
      unsigned X2a = g ? k2a : k3a, X2b = g ? k2b : k3b;
      X1a = __shfl_xor(X1a, 32); X1b = __shfl_xor(X1b, 32);
      X2a = __shfl_xor(X2a, 32); X2b = __shfl_xor(X2b, 32);
      pav[msub*2]     = g ? make_uint4(X1a, X1b, k1a, k1b)
                          : make_uint4(k0a, k0b, X1a, X1b);
      pav[msub*2 + 1] = g ? make_uint4(X2a, X2b, k3a, k3b)
                          : make_uint4(k2a, k2b, X2a, X2b);
    }
    ps += __shfl_xor(ps, 32);
    L += ps;

    __builtin_amdgcn_s_setprio(1);
    #pragma unroll
    for (int ks = 0; ks < 4; ++ks) {
      bf16x8 pa = __builtin_bit_cast(bf16x8, pav[ks]);
      #pragma unroll
      for (int ct = 0; ct < 8; ++ct) {
        bf16x8 vv = *(const bf16x8*)((char*)VlG + (ct*32 + l31)*256
                     + ((h*128 + ks*32 + g*16) ^ ((l31 & 15) << 4)));
        acc[ct] = __builtin_amdgcn_mfma_f32_32x32x16_bf16(pa, vv, acc[ct], 0,0,0);
      }
    }
    __builtin_amdgcn_s_setprio(0);

    if (mt + 1 < 32) {
      *(bf16x8*)(Kl + grp*4096 + (h^1)*2048 + t4*8) = stK;
      #pragma unroll
      for (int i = 0; i < 8; ++i) {
        int q = i*256 + t4;
        int c = q >> 3, slot = q & 7;
        *(bf16x8*)((char*)VlG + c*256 + (((h ^ 1)*128 + slot*16) ^ ((c & 15) << 4))) = stV[i];
      }
    }
    __syncthreads();
    h ^= 1;
  }

  // merge grp1 -> grp0 (exact sums)
  float* mb = (float*)Kl;
  mb[t] = L;
  __syncthreads();
  float Ln = L + mb[t ^ 256];

  float* vb = (float*)Vl;
  #pragma unroll
  for (int pass = 0; pass < 2; ++pass) {
    __syncthreads();
    if (grp == 1) {
      #pragma unroll
      for (int cc = 0; cc < 4; ++cc) {
        int ct = pass*4 + cc;
        #pragma unroll
        for (int r = 0; r < 16; ++r)
          vb[(cc*256 + t4)*16 + r] = acc[ct][r];
      }
    }
    __syncthreads();
    if (grp == 0) {
      #pragma unroll
      for (int cc = 0; cc < 4; ++cc) {
        int ct = pass*4 + cc;
        #pragma unroll
        for (int r = 0; r < 16; ++r)
          acc[ct][r] += vb[(cc*256 + t4)*16 + r];
      }
    }
  }
  __syncthreads();   // vb reads done; O region may now be overwritten

  // grp0: normalized O -> LDS (bf16, [128][512B] XOR layout); NOTE row-broadcast lrr[r]
  char* ldsO = lds + 16384;
  if (grp == 0) {
    float lr = 1.0f / Ln;
    float lrr[16];
    #pragma unroll
    for (int r = 0; r < 16; ++r)
      lrr[r] = __shfl(lr, (r&3) + 8*(r>>2) + 4*g, 32);
    #pragma unroll
    for (int ct = 0; ct < 8; ++ct) {
      #pragma unroll
      for (int r = 0; r < 16; ++r) {
        int n = wg*32 + (r&3) + 8*(r>>2) + 4*g;
        int c = ct*32 + l31;
        *(u16*)(ldsO + n*512 + ((c*2) ^ ((n & 7) << 4))) = f2b(acc[ct][r] * lrr[r]);
      }
    }
  }
  __syncthreads();

  // ---------------- FFN ----------------
  int lw = (w & 1) * 64, sw = (w >> 1) * 64;
  char* ldsH1  = lds + 81920;
  char* ldsBh1 = lds + 81920;    // phase-1 W1 staging (dead before H1 write)
  char* ldsBl1 = lds + 114688;
  char* ldsBh2 = lds + 16384;    // phase-2 W2 staging (O region, dead)
  char* ldsBl2 = lds + 49152;

  f32x16 fa[2][2];
  #pragma unroll
  for (int i = 0; i < 2; ++i)
    #pragma unroll
    for (int j = 0; j < 2; ++j)
      #pragma unroll
      for (int r = 0; r < 16; ++r) fa[i][j][r] = 0.f;

  // phase 1: H1 = relu(O @ W1^T + b1)
  uint4 rBh[4], rBl[4];
  #pragma unroll
  for (int c = 0; c < 4; ++c) {
    int u = c*512 + t, row = u >> 3, slot = u & 7;
    rBh[c] = *(const uint4*)(W1h + (size_t)row*C_DIM + slot*8);
    rBl[c] = *(const uint4*)(W1l + (size_t)row*C_DIM + slot*8);
  }
  for (int bk = 0; bk < 4; ++bk) {
    __syncthreads();
    #pragma unroll
    for (int c = 0; c < 4; ++c) {
      int u = c*512 + t, row = u >> 3, slot = u & 7;
      int off = row*128 + ((slot*16) ^ ((row & 7) << 4));
      *(uint4*)(ldsBh1 + off) = rBh[c];
      *(uint4*)(ldsBl1 + off) = rBl[c];
    }
    __syncthreads();
    if (bk < 3) {
      #pragma unroll
      for (int c = 0; c < 4; ++c) {
        int u = c*512 + t, row = u >> 3, slot = u & 7;
        rBh[c] = *(const uint4*)(W1h + (size_t)row*C_DIM + (bk+1)*64 + slot*8);
        rBl[c] = *(const uint4*)(W1l + (size_t)row*C_DIM + (bk+1)*64 + slot*8);
      }
    }
    #pragma unroll
    for (int ks = 0; ks < 4; ++ks) {
      int ko = ks*32 + g*16;
      int kb = bk*128 + ko;
      bf16x8 ah0 = *(const bf16x8*)(ldsO + (lw + l31)*512      + (kb ^ swz));
      bf16x8 ah1 = *(const bf16x8*)(ldsO + (lw + 32 + l31)*512 + (kb ^ swz));
      bf16x8 bh0 = *(const bf16x8*)(ldsBh1 + (sw + l31)*128      + (ko ^ swz));
      bf16x8 bh1 = *(const bf16x8*)(ldsBh1 + (sw + 32 + l31)*128 + (ko ^ swz));
      bf16x8 bl0 = *(const bf16x8*)(ldsBl1 + (sw + l31)*128      + (ko ^ swz));
      bf16x8 bl1 = *(const bf16x8*)(ldsBl1 + (sw + 32 + l31)*128 + (ko ^ swz));
      fa[0][0] = __builtin_amdgcn_mfma_f32_32x32x16_bf16(ah0, bh0, fa[0][0], 0,0,0);
      fa[0][1] = __builtin_amdgcn_mfma_f32_32x32x16_bf16(ah0, bh1, fa[0][1], 0,0,0);
      fa[1][0] = __builtin_amdgcn_mfma_f32_32x32x16_bf16(ah1, bh0, fa[1][0], 0,0,0);
      fa[1][1] = __builtin_amdgcn_mfma_f32_32x32x16_bf16(ah1, bh1, fa[1][1], 0,0,0);
      fa[0][0] = __builtin_amdgcn_mfma_f32_32x32x16_bf16(ah0, bl0, fa[0][0], 0,0,0);
      fa[0][1] = __builtin_amdgcn_mfma_f32_32x32x16_bf16(ah0, bl1, fa[0][1], 0,0,0);
      fa[1][0] = __builtin_amdgcn_mfma_f32_32x32x16_bf16(ah1, bl0, fa[1][0], 0,0,0);
      fa[1][1] = __builtin_amdgcn_mfma_f32_32x32x16_bf16(ah1, bl1, fa[1][1], 0,0,0);
    }
  }
  __syncthreads();   // W1 staging reads done; region becomes H1

  #pragma unroll
  for (int j = 0; j < 2; ++j) {
    int o = sw + j*32 + l31;
    float bvv = b1[o];
    #pragma unroll
    for (int i = 0; i < 2; ++i)
      #pragma unroll
      for (int r = 0; r < 16; ++r) {
        int n = lw + i*32 + (r&3) + 8*(r>>2) + 4*g;
        *(u16*)(ldsH1 + n*512 + ((o*2) ^ ((n & 7) << 4))) = f2b(fmaxf(fa[i][j][r] + bvv, 0.f));
      }
  }

  #pragma unroll
  for (int i = 0; i < 2; ++i)
    #pragma unroll
    for (int j = 0; j < 2; ++j)
      #pragma unroll
      for (int r = 0; r < 16; ++r) fa[i][j][r] = 0.f;

  // phase 2: out = H1 @ W2^T + b2
  #pragma unroll
  for (int c = 0; c < 4; ++c) {
    int u = c*512 + t, row = u >> 3, slot = u & 7;
    rBh[c] = *(const uint4*)(W2h + (size_t)row*C_DIM + slot*8);
    rBl[c] = *(const uint4*)(W2l + (size_t)row*C_DIM + slot*8);
  }
  for (int bk = 0; bk < 4; ++bk) {
    __syncthreads();   // first iter: H1 writes visible
    #pragma unroll
    for (int c = 0; c < 4; ++c) {
      int u = c*512 + t, row = u >> 3, slot = u & 7;
      int off = row*128 + ((slot*16) ^ ((row & 7) << 4));
      *(uint4*)(ldsBh2 + off) = rBh[c];
      *(uint4*)(ldsBl2 + off) = rBl[c];
    }
    __syncthreads();
    if (bk < 3) {
      #pragma unroll
      for (int c = 0; c < 4; ++c) {
        int u = c*512 + t, row = u >> 3, slot = u & 7;
        rBh[c] = *(const uint4*)(W2h + (size_t)row*C_DIM + (bk+1)*64 + slot*8);
        rBl[c] = *(const uint4*)(W2l + (size_t)row*C_DIM + (bk+1)*64 + slot*8);
      }
    }
    #pragma unroll
    for (int ks = 0; ks < 4; ++ks) {
      int ko = ks*32 + g*16;
      int kb = bk*128 + ko;
      bf16x8 ah0 = *(const bf16x8*)(ldsH1 + (lw + l31)*512      + (kb ^ swz));
      bf16x8 ah1 = *(const bf16x8*)(ldsH1 + (lw + 32 + l31)*512 + (kb ^ swz));
      bf16x8 bh0 = *(const bf16x8*)(ldsBh2 + (sw + l31)*128      + (ko ^ swz));
      bf16x8 bh1 = *(const bf16x8*)(ldsBh2 + (sw + 32 + l31)*128 + (ko ^ swz));
      bf16x8 bl0 = *(const bf16x8*)(ldsBl2 + (sw + l31)*128      + (ko ^ swz));
      bf16x8 bl1 = *(const bf16x8*)(ldsBl2 + (sw + 32 + l31)*128 + (ko ^ swz));
      fa[0][0] = __builtin_amdgcn_mfma_f32_32x32x16_bf16(ah0, bh0, fa[0][0], 0,0,0);
      fa[0][1] = __builtin_amdgcn_mfma_f32_32x32x16_bf16(ah0, bh1, fa[0][1], 0,0,0);
      fa[1][0] = __builtin_amdgcn_mfma_f32_32x32x16_bf16(ah1, bh0, fa[1][0], 0,0,0);
      fa[1][1] = __builtin_amdgcn_mfma_f32_32x32x16_bf16(ah1, bh1, fa[1][1], 0,0,0);
      fa[0][0] = __builtin_amdgcn_mfma_f32_32x32x16_bf16(ah0, bl0, fa[0][0], 0,0,0);
      fa[0][1] = __builtin_amdgcn_mfma_f32_32x32x16_bf16(ah0, bl1, fa[0][1], 0,0,0);
      fa[1][0] = __builtin_amdgcn_mfma_f32_32x32x16_bf16(ah1, bl0, fa[1][0], 0,0,0);
      fa[1][1] = __builtin_amdgcn_mfma_f32_32x32x16_bf16(ah1, bl1, fa[1][1], 0,0,0);
    }
  }

  // bias + LN partial sums
  float s = 0.f, s2 = 0.f;
  #pragma unroll
  for (int j = 0; j < 2; ++j) {
    float bvv = b2[sw + j*32 + l31];
    #pragma unroll
    for (int i = 0; i < 2; ++i)
      #pragma unroll
      for (int r = 0; r < 16; ++r) {
        fa[i][j][r] += bvv;
        s += fa[i][j][r];
        s2 += fa[i][j][r]*fa[i][j][r];
      }
  }
  for (int off = 32; off; off >>= 1) {
    s  += __shfl_down(s, off, 64);
    s2 += __shfl_down(s2, off, 64);
  }
  __syncthreads();
  float* sc = (float*)lds;   // Kl region, dead
  if (lane == 0) { sc[w*2] = s; sc[w*2+1] = s2; }
  __syncthreads();
  if (t == 0) {
    int slot = bb*32 + (id >> 3);
    float S = 0.f, S2 = 0.f;
    #pragma unroll
    for (int q = 0; q < 8; ++q) { S += sc[q*2]; S2 += sc[q*2+1]; }
    part[slot*2]     = S;
    part[slot*2 + 1] = S2;
  }

  // transposed f32 store via LDS: 4 quarter-passes (64 short rows each) in O region
  float* Ob = out + (size_t)bb * (size_t)N_TOK * C_DIM;   // [c][n]
  int l0 = n0;
  for (int qp = 0; qp < 4; ++qp) {
    __syncthreads();
    if ((w >> 1) == qp) {
      #pragma unroll
      for (int j = 0; j < 2; ++j) {
        int sl = j*32 + l31;                 // 0..63 within quarter
        #pragma unroll
        for (int i = 0; i < 2; ++i)
          #pragma unroll
          for (int q = 0; q < 4; ++q) {
            int lbase = lw + i*32 + 8*q + 4*g;
            float4 vv;
            vv.x = fa[i][j][q*4+0];
            vv.y = fa[i][j][q*4+1];
            vv.z = fa[i][j][q*4+2];
            vv.w = fa[i][j][q*4+3];
            *(float4*)(ldsO + sl*528 + lbase*4) = vv;
          }
      }
    }
    __syncthreads();
    #pragma unroll
    for (int p2 = 0; p2 < 4; ++p2) {
      int idx = p2*512 + t;
      int sl = idx >> 5, col = (idx & 31)*4;
      float4 v = *(const float4*)(ldsO + sl*528 + col*4);
      *(float4*)(Ob + (size_t)(qp*64 + sl)*(size_t)N_TOK + l0 + col) = v;
    }
  }
}

// ---------------- ln_apply with inline stats reduce ----------------
__global__ __launch_bounds__(256) void ln_apply_kernel(
    float* __restrict__ H, const float* __restrict__ gamma,
    const float* __restrict__ beta, const float* __restrict__ part)
{
  __shared__ float st[2];
  int base = blockIdx.x * 4096;
  int bb = base >> 20;
  int t = threadIdx.x;
  if (t < 64) {
    float s = 0.f, s2 = 0.f;
    if (t < 32) { s = part[(bb*32 + t)*2]; s2 = part[(bb*32 + t)*2 + 1]; }
    for (int off = 16; off; off >>= 1) {
      s  += __shfl_down(s, off, 64);
      s2 += __shfl_down(s2, off, 64);
    }
    if (t == 0) {
      float mean = s * (1.0f/1048576.0f);
      float var  = s2 * (1.0f/1048576.0f) - mean*mean;
      st[0] = mean;
      st[1] = rsqrtf(var + 1e-5f);
    }
  }
  __syncthreads();
  float mean = st[0], istd = st[1];
  #pragma unroll
  for (int k = 0; k < 4; ++k) {
    int e = base + (k*256 + t)*4;
    int rem = e & ((1 << 20) - 1);
    float4 h = *(float4*)(H + (size_t)e);
    float4 g = *(const float4*)(gamma + rem);
    float4 b = *(const float4*)(beta + rem);
    h.x = (h.x - mean)*istd*g.x + b.x;
    h.y = (h.y - mean)*istd*g.y + b.y;
    h.z = (h.z - mean)*istd*g.z + b.z;
    h.w = (h.w - mean)*istd*g.w + b.w;
    *(float4*)(H + (size_t)e) = h;
  }
}

extern "C" void kernel_launch(void* const* d_in, const int* in_sizes, int n_in,
                              void* d_out, int out_size, void* d_ws, size_t ws_size,
                              hipStream_t stream) {
  (void)in_sizes; (void)n_in; (void)out_size; (void)ws_size;
  const float* x  = (const float*)d_in[0];
  const float* y  = (const float*)d_in[1];
  const float* Wq = (const float*)d_in[2];
  const float* bq = (const float*)d_in[3];
  const float* Wk = (const float*)d_in[4];
  const float* bk = (const float*)d_in[5];
  const float* Wv = (const float*)d_in[6];
  const float* bv = (const float*)d_in[7];
  const float* W1 = (const float*)d_in[8];
  const float* b1 = (const float*)d_in[9];
  const float* W2 = (const float*)d_in[10];
  const float* b2 = (const float*)d_in[11];
  const float* gamma = (const float*)d_in[12];
  const float* beta  = (const float*)d_in[13];
  float* out = (float*)d_out;

  char* ws = (char*)d_ws;
  u16* xs_hi = (u16*)(ws);
  u16* ys_hi = (u16*)(ws + (8ull<<20));
  u16* Q     = (u16*)(ws + (16ull<<20));
  u16* Kp    = (u16*)(ws + (18ull<<20));
  u16* Vt    = (u16*)(ws + (20ull<<20));
  u16* Wvh   = (u16*)(ws + (52ull<<20));
  u16* Wvl   = Wvh + 65536;
  u16* W1h   = Wvh + 2*65536;
  u16* W1l   = Wvh + 3*65536;
  u16* W2h   = Wvh + 4*65536;
  u16* W2l   = Wvh + 5*65536;
  u16* Wqh   = Wvh + 6*65536;
  u16* Wql   = Wqh + 8192;
  u16* Wkh   = Wqh + 2*8192;
  u16* Wkl   = Wqh + 3*8192;
  float* part  = (float*)(ws + (53ull<<20));

  prep_kernel <<<2880, 256, 0, stream>>>(
      x, y, xs_hi, ys_hi, Wv, W1, W2, Wq, Wk,
      Wvh, Wvl, W1h, W1l, W2h, W2l, Wqh, Wql, Wkh, Wkl);
  pv_qk_kernel<<<768, 256, 0, stream>>>(
      xs_hi, ys_hi, Wvh, Wvl, Wqh, Wql, Wkh, Wkl, bv, bq, bk, Vt, Q, Kp);
  attn_ffn_kernel<<<256, 512, 0, stream>>>(
      Q, Kp, Vt, W1h, W1l, W2h, W2l, b1, b2, out, part);
  ln_apply_kernel <<<2048, 256, 0, stream>>>(out, gamma, beta, part);
}